// Round 8
// baseline (274.248 us; speedup 1.0000x reference)
//
#include <hip/hip_runtime.h>

#define D  128
#define NF 3
#define V  8
#define STRIDE 64          // padded-CSR slots per node; max degree ~35 << 64
#define POISON 0xAAAAAAAAu

typedef __attribute__((ext_vector_type(8))) short short8;
typedef __attribute__((ext_vector_type(4))) float f32x4;

__device__ inline unsigned short f2bf(float x) {
    unsigned u = __builtin_bit_cast(unsigned, x);
    return (unsigned short)((u + 0x7FFFu + ((u >> 16) & 1u)) >> 16);   // RNE
}
__device__ inline float bflo(unsigned u) {
    return __builtin_bit_cast(float, u << 16);
}
__device__ inline float bfhi(unsigned u) {
    return __builtin_bit_cast(float, u & 0xFFFF0000u);
}

// ---------------- Dispatch A: build everything, no ordering deps ------------
// roles by blockIdx:
//  [0, eb)        edge role: rank = poison-aware CAS-inc of count[dst];
//                 packed[dst*STRIDE + rank] = src | cmb<<16
//  [eb, eb+256)   combined edge-emb table Tb[512][128] bf16
//  [eb+256,+64)   W -> B-fragment-order bf16 WB[16384]
//  rest           nfeat fp32 -> bf16 (4 floats/thread)
// count[] is NOT pre-zeroed: 0xAA poison (or 0) is treated as zero by the CAS.

__global__ __launch_bounds__(256) void build_kernel(
    const int* __restrict__ src, const int* __restrict__ dst,
    const int* __restrict__ eidx, const float* __restrict__ emb,
    const float* __restrict__ Wm, const float* __restrict__ nfeat,
    unsigned* __restrict__ count, unsigned* __restrict__ packed,
    unsigned short* __restrict__ Tb, unsigned short* __restrict__ WB,
    unsigned* __restrict__ nfb32, int E, int eb)
{
    int b = blockIdx.x, t = threadIdx.x;
    if (b < eb) {
        int e = b * 256 + t;
        if (e < E) {
            int d = dst[e];
            int i0 = eidx[e * NF], i1 = eidx[e * NF + 1], i2 = eidx[e * NF + 2];
            unsigned rec = (unsigned)src[e]
                         | ((unsigned)(i0 + (i1 << 3) + (i2 << 6)) << 16);
            // poison-aware increment, returns previous logical count
            unsigned old = count[d];
            unsigned rank;
            for (;;) {
                unsigned base = (old == POISON) ? 0u : old;
                unsigned prev = atomicCAS(&count[d], old, base + 1u);
                if (prev == old) { rank = base; break; }
                old = prev;
            }
            packed[d * STRIDE + rank] = rec;
        }
    } else if (b < eb + 256) {
        int tid = (b - eb) * 256 + t;              // 0..65535
        int cmb = tid >> 7, c = tid & 127;
        float s = emb[(cmb & 7) * D + c]
                + emb[(V + ((cmb >> 3) & 7)) * D + c]
                + emb[(2 * V + (cmb >> 6)) * D + c];
        Tb[tid] = f2bf(s);
    } else if (b < eb + 320) {
        // WB[((n*4+ks)*64+ln)*8+j] = bf16(W[ks*32+(ln>>4)*8+j][n*16+(ln&15)])
        int tid = (b - (eb + 256)) * 256 + t;      // 0..16383
        int j = tid & 7, ln = (tid >> 3) & 63, ks = (tid >> 9) & 3, n = tid >> 11;
        int k = ks * 32 + ((ln >> 4) << 3) + j;
        int c = n * 16 + (ln & 15);
        WB[tid] = f2bf(Wm[k * D + c]);
    } else {
        int tid = (b - (eb + 320)) * 256 + t;      // 4 floats each
        float4 v = ((const float4*)nfeat)[tid];
        nfb32[tid * 2 + 0] = (unsigned)f2bf(v.x) | ((unsigned)f2bf(v.y) << 16);
        nfb32[tid * 2 + 1] = (unsigned)f2bf(v.z) | ((unsigned)f2bf(v.w) << 16);
    }
}

// ---------------- Dispatch B: fused gather + MFMA projection ----------------
// Block = 16 nodes, 4 waves. Wave w gathers nodes row0+w*4..+3 into the LDS
// h-tile (single batch: deg <= 64), then computes cols [w*32, w*32+32).

__global__ __launch_bounds__(256) void fused_gp(
    const float* __restrict__ nfeat,
    const unsigned* __restrict__ nfb32,
    const unsigned* __restrict__ Tb32,
    const unsigned* __restrict__ packed,
    const unsigned* __restrict__ count,
    const unsigned short* __restrict__ WB,
    const float* __restrict__ bias,
    float* __restrict__ out, int N)
{
    __shared__ unsigned short hA[16][136];   // +8 pad
    int t = threadIdx.x, w = t >> 6, lane = t & 63;
    int quad = lane >> 4, l15 = lane & 15;
    int row0 = blockIdx.x * 16;

    // Prefetch this wave's B fragments + bias (independent of gather)
    short8 bf[2][4];
#pragma unroll
    for (int ni = 0; ni < 2; ++ni)
#pragma unroll
        for (int ks = 0; ks < 4; ++ks)
            bf[ni][ks] = *(const short8*)&WB[(((w * 2 + ni) * 4 + ks) * 64 + lane) * 8];
    float bvv[2] = { bias[w * 32 + l15], bias[w * 32 + 16 + l15] };

    // Phase 1: gather (single 64-edge batch per node)
    for (int i = 0; i < 4; ++i) {
        int n = row0 + w * 4 + i;
        if (n >= N) break;
        unsigned craw = count[n];
        int cnt = (craw == POISON) ? 0 : (int)craw;   // untouched => degree 0
        float2 acc = ((const float2*)nfeat)[n * 64 + lane];   // self term fp32
        unsigned rec = (lane < cnt) ? packed[n * STRIDE + lane] : 0u;
        int j = 0;
        for (; j + 4 <= cnt; j += 4) {
            unsigned u0 = __shfl((int)rec, j);
            unsigned u1 = __shfl((int)rec, j + 1);
            unsigned u2 = __shfl((int)rec, j + 2);
            unsigned u3 = __shfl((int)rec, j + 3);
            unsigned a0 = nfb32[(u0 & 0xFFFFu) * 64 + lane];
            unsigned t0 = Tb32[(u0 >> 16) * 64 + lane];
            unsigned a1 = nfb32[(u1 & 0xFFFFu) * 64 + lane];
            unsigned t1 = Tb32[(u1 >> 16) * 64 + lane];
            unsigned a2 = nfb32[(u2 & 0xFFFFu) * 64 + lane];
            unsigned t2 = Tb32[(u2 >> 16) * 64 + lane];
            unsigned a3 = nfb32[(u3 & 0xFFFFu) * 64 + lane];
            unsigned t3 = Tb32[(u3 >> 16) * 64 + lane];
            acc.x += (bflo(a0) + bflo(t0)) + (bflo(a1) + bflo(t1))
                   + (bflo(a2) + bflo(t2)) + (bflo(a3) + bflo(t3));
            acc.y += (bfhi(a0) + bfhi(t0)) + (bfhi(a1) + bfhi(t1))
                   + (bfhi(a2) + bfhi(t2)) + (bfhi(a3) + bfhi(t3));
        }
        for (; j < cnt; ++j) {
            unsigned u = __shfl((int)rec, j);
            unsigned a = nfb32[(u & 0xFFFFu) * 64 + lane];
            unsigned tt = Tb32[(u >> 16) * 64 + lane];
            acc.x += bflo(a) + bflo(tt);
            acc.y += bfhi(a) + bfhi(tt);
        }
        float inv = 1.0f / (float)(cnt + 1);
        acc.x *= inv; acc.y *= inv;
        *(unsigned*)&hA[w * 4 + i][2 * lane] =
            (unsigned)f2bf(acc.x) | ((unsigned)f2bf(acc.y) << 16);
    }
    __syncthreads();

    // Phase 2: 16x128 output tile; wave w does cols [w*32, w*32+32)
    short8 a[4];
#pragma unroll
    for (int ks = 0; ks < 4; ++ks)
        a[ks] = *(const short8*)&hA[l15][ks * 32 + quad * 8];

#pragma unroll
    for (int ni = 0; ni < 2; ++ni) {
        f32x4 acc4 = {0.0f, 0.0f, 0.0f, 0.0f};
#pragma unroll
        for (int ks = 0; ks < 4; ++ks)
            acc4 = __builtin_amdgcn_mfma_f32_16x16x32_bf16(a[ks], bf[ni][ks], acc4, 0, 0, 0);
        int col = w * 32 + ni * 16 + l15;
#pragma unroll
        for (int rg = 0; rg < 4; ++rg) {
            int row = row0 + quad * 4 + rg;
            if (row < N) out[row * D + col] = acc4[rg] + bvv[ni];
        }
    }
}

extern "C" void kernel_launch(void* const* d_in, const int* in_sizes, int n_in,
                              void* d_out, int out_size, void* d_ws, size_t ws_size,
                              hipStream_t stream)
{
    const float* nfeat = (const float*)d_in[0];
    const int*   src   = (const int*)  d_in[1];
    const int*   dst   = (const int*)  d_in[2];
    const int*   eidx  = (const int*)  d_in[3];
    const float* emb   = (const float*)d_in[4];
    const float* Wm    = (const float*)d_in[5];
    const float* bias  = (const float*)d_in[6];
    float* out = (float*)d_out;

    int N = in_sizes[0] / D;   // 50000
    int E = in_sizes[1];       // 600000
    int eb = (E + 255) / 256;  // 2344

    // ws: count[N] | packed[N*STRIDE] | Tb[65536 u16] | WB[16384 u16]
    //     | nfb[N*64 u32]   (~26 MB of the 256 MB ws)
    unsigned* count  = (unsigned*)d_ws;
    unsigned* packed = count + N;
    unsigned short* Tb = (unsigned short*)(packed + (size_t)N * STRIDE);
    unsigned short* WB = Tb + 512 * 128;
    unsigned* nfb32 = (unsigned*)(WB + 16384);

    int nfb_blocks = (N * D / 4 + 255) / 256;   // 6250
    build_kernel<<<eb + 320 + nfb_blocks, 256, 0, stream>>>(
        src, dst, eidx, emb, Wm, nfeat, count, packed, Tb, WB, nfb32, E, eb);
    fused_gp<<<(N + 15) / 16, 256, 0, stream>>>(
        nfeat, nfb32, (const unsigned*)Tb, packed, count, WB, bias, out, N);
}

// Round 9
// 222.508 us; speedup vs baseline: 1.2325x; 1.2325x over previous
//
#include <hip/hip_runtime.h>

#define D    128
#define NF   3
#define V    8
#define BCAP 768   // bucket capacity: 32 nodes * lambda 12 = 384 expected, 19-sigma margin
#define NCAP 64    // per-node LDS list capacity (max degree ~40 expected)

typedef __attribute__((ext_vector_type(8))) short short8;
typedef __attribute__((ext_vector_type(4))) float f32x4;

__device__ inline unsigned short f2bf(float x) {
    unsigned u = __builtin_bit_cast(unsigned, x);
    return (unsigned short)((u + 0x7FFFu + ((u >> 16) & 1u)) >> 16);   // RNE
}
__device__ inline float bflo(unsigned u) {
    return __builtin_bit_cast(float, u << 16);
}
__device__ inline float bfhi(unsigned u) {
    return __builtin_bit_cast(float, u & 0xFFFF0000u);
}

// ---------------- Dispatch A: build ----------------
// roles by blockIdx:
//  [0, eb)       edge role: bucket = dst>>5; dense append of
//                rec = src | cmb<<16 | (dst&31)<<25 at cursor[bucket]++
//  [eb, eb+256)  combined edge-emb table Tb[512][128] bf16
//  [eb+256,+64)  W -> B-fragment-order bf16 WB[16384]
//  rest          nfeat fp32 -> bf16 (4 floats/thread)

__global__ __launch_bounds__(256) void build_kernel(
    const int* __restrict__ src, const int* __restrict__ dst,
    const int* __restrict__ eidx, const float* __restrict__ emb,
    const float* __restrict__ Wm, const float* __restrict__ nfeat,
    unsigned* __restrict__ cursor, unsigned* __restrict__ bucket,
    unsigned short* __restrict__ Tb, unsigned short* __restrict__ WB,
    unsigned* __restrict__ nfb32, int E, int eb)
{
    int b = blockIdx.x, t = threadIdx.x;
    if (b < eb) {
        int e = b * 256 + t;
        if (e < E) {
            int dd = dst[e];
            int i0 = eidx[e * NF], i1 = eidx[e * NF + 1], i2 = eidx[e * NF + 2];
            unsigned rec = (unsigned)src[e]
                         | ((unsigned)(i0 + (i1 << 3) + (i2 << 6)) << 16)
                         | ((unsigned)(dd & 31) << 25);
            int bk = dd >> 5;
            unsigned pos = atomicAdd(&cursor[bk], 1u);
            bucket[(size_t)bk * BCAP + pos] = rec;   // dense within bucket
        }
    } else if (b < eb + 256) {
        int tid = (b - eb) * 256 + t;              // 0..65535
        int cmb = tid >> 7, c = tid & 127;
        float s = emb[(cmb & 7) * D + c]
                + emb[(V + ((cmb >> 3) & 7)) * D + c]
                + emb[(2 * V + (cmb >> 6)) * D + c];
        Tb[tid] = f2bf(s);
    } else if (b < eb + 320) {
        // WB[((n*4+ks)*64+ln)*8+j] = bf16(W[ks*32+(ln>>4)*8+j][n*16+(ln&15)])
        int tid = (b - (eb + 256)) * 256 + t;      // 0..16383
        int j = tid & 7, ln = (tid >> 3) & 63, ks = (tid >> 9) & 3, n = tid >> 11;
        int k = ks * 32 + ((ln >> 4) << 3) + j;
        int c = n * 16 + (ln & 15);
        WB[tid] = f2bf(Wm[k * D + c]);
    } else {
        int tid = (b - (eb + 320)) * 256 + t;      // 4 floats each
        float4 v = ((const float4*)nfeat)[tid];
        nfb32[tid * 2 + 0] = (unsigned)f2bf(v.x) | ((unsigned)f2bf(v.y) << 16);
        nfb32[tid * 2 + 1] = (unsigned)f2bf(v.z) | ((unsigned)f2bf(v.w) << 16);
    }
}

// ---------------- Dispatch B: bin + gather + MFMA projection ----------------
// One block per bucket (32 nodes). Bin bucket records into per-node LDS lists,
// gather (wave w handles nodes w*8..w*8+7), then 32x128 MFMA projection.

__global__ __launch_bounds__(256) void fused_gp(
    const float* __restrict__ nfeat,
    const unsigned* __restrict__ nfb32,
    const unsigned* __restrict__ Tb32,
    const unsigned* __restrict__ bucket,
    const unsigned* __restrict__ cursor,
    const unsigned short* __restrict__ WB,
    const float* __restrict__ bias,
    float* __restrict__ out, int N)
{
    __shared__ unsigned list[32][NCAP];
    __shared__ int lcnt[32];
    __shared__ unsigned short hA[32][136];   // +8 pad

    int t = threadIdx.x, w = t >> 6, lane = t & 63;
    int quad = lane >> 4, l15 = lane & 15;
    int bk = blockIdx.x;
    int row0 = bk * 32;

    // Prefetch this wave's B fragments + bias (independent of everything)
    short8 bf[2][4];
#pragma unroll
    for (int ni = 0; ni < 2; ++ni)
#pragma unroll
        for (int ks = 0; ks < 4; ++ks)
            bf[ni][ks] = *(const short8*)&WB[(((w * 2 + ni) * 4 + ks) * 64 + lane) * 8];
    float bvv[2] = { bias[w * 32 + l15], bias[w * 32 + 16 + l15] };

    // ---- bin bucket records into per-node lists ----
    if (t < 32) lcnt[t] = 0;
    __syncthreads();
    int bcnt = (int)cursor[bk];
    for (int i = t; i < bcnt; i += 256) {
        unsigned rec = bucket[(size_t)bk * BCAP + i];
        int n5 = (int)(rec >> 25);
        int p = atomicAdd(&lcnt[n5], 1);
        list[n5][p] = rec;
    }
    __syncthreads();

    // ---- gather: wave w -> nodes w*8 .. w*8+7 ----
    for (int k = 0; k < 8; ++k) {
        int n5 = w * 8 + k;
        int n = row0 + n5;
        if (n >= N) break;
        int cnt = lcnt[n5];
        float2 acc = ((const float2*)nfeat)[n * 64 + lane];   // self term fp32
        int j = 0;
        for (; j + 4 <= cnt; j += 4) {
            uint4 r4 = *(const uint4*)&list[n5][j];   // LDS broadcast b128
            unsigned a0 = nfb32[(r4.x & 0xFFFFu) * 64 + lane];
            unsigned t0 = Tb32[((r4.x >> 16) & 0x1FFu) * 64 + lane];
            unsigned a1 = nfb32[(r4.y & 0xFFFFu) * 64 + lane];
            unsigned t1 = Tb32[((r4.y >> 16) & 0x1FFu) * 64 + lane];
            unsigned a2 = nfb32[(r4.z & 0xFFFFu) * 64 + lane];
            unsigned t2 = Tb32[((r4.z >> 16) & 0x1FFu) * 64 + lane];
            unsigned a3 = nfb32[(r4.w & 0xFFFFu) * 64 + lane];
            unsigned t3 = Tb32[((r4.w >> 16) & 0x1FFu) * 64 + lane];
            acc.x += (bflo(a0) + bflo(t0)) + (bflo(a1) + bflo(t1))
                   + (bflo(a2) + bflo(t2)) + (bflo(a3) + bflo(t3));
            acc.y += (bfhi(a0) + bfhi(t0)) + (bfhi(a1) + bfhi(t1))
                   + (bfhi(a2) + bfhi(t2)) + (bfhi(a3) + bfhi(t3));
        }
        for (; j < cnt; ++j) {
            unsigned rec = list[n5][j];
            unsigned a = nfb32[(rec & 0xFFFFu) * 64 + lane];
            unsigned tt = Tb32[((rec >> 16) & 0x1FFu) * 64 + lane];
            acc.x += bflo(a) + bflo(tt);
            acc.y += bfhi(a) + bfhi(tt);
        }
        float inv = 1.0f / (float)(cnt + 1);
        acc.x *= inv; acc.y *= inv;
        *(unsigned*)&hA[n5][2 * lane] =
            (unsigned)f2bf(acc.x) | ((unsigned)f2bf(acc.y) << 16);
    }
    __syncthreads();

    // ---- projection: two 16-row halves; wave w does cols [w*32, w*32+32) ----
#pragma unroll
    for (int half = 0; half < 2; ++half) {
        short8 a[4];
#pragma unroll
        for (int ks = 0; ks < 4; ++ks)
            a[ks] = *(const short8*)&hA[half * 16 + l15][ks * 32 + quad * 8];

#pragma unroll
        for (int ni = 0; ni < 2; ++ni) {
            f32x4 acc4 = {0.0f, 0.0f, 0.0f, 0.0f};
#pragma unroll
            for (int ks = 0; ks < 4; ++ks)
                acc4 = __builtin_amdgcn_mfma_f32_16x16x32_bf16(a[ks], bf[ni][ks], acc4, 0, 0, 0);
            int col = w * 32 + ni * 16 + l15;
#pragma unroll
            for (int rg = 0; rg < 4; ++rg) {
                int row = row0 + half * 16 + quad * 4 + rg;
                if (row < N) out[row * D + col] = acc4[rg] + bvv[ni];
            }
        }
    }
}

extern "C" void kernel_launch(void* const* d_in, const int* in_sizes, int n_in,
                              void* d_out, int out_size, void* d_ws, size_t ws_size,
                              hipStream_t stream)
{
    const float* nfeat = (const float*)d_in[0];
    const int*   src   = (const int*)  d_in[1];
    const int*   dst   = (const int*)  d_in[2];
    const int*   eidx  = (const int*)  d_in[3];
    const float* emb   = (const float*)d_in[4];
    const float* Wm    = (const float*)d_in[5];
    const float* bias  = (const float*)d_in[6];
    float* out = (float*)d_out;

    int N = in_sizes[0] / D;        // 50000
    int E = in_sizes[1];            // 600000
    int eb = (E + 255) / 256;       // 2344
    int NBK = (N + 31) / 32;        // 1563 buckets

    // ws: cursor[2048] | bucket[NBK*BCAP] | Tb[65536 u16] | WB[16384 u16]
    //     | nfb[N*64 u32]   (~18 MB)
    unsigned* cursor = (unsigned*)d_ws;
    unsigned* bucket = cursor + 2048;
    unsigned short* Tb = (unsigned short*)(bucket + (size_t)NBK * BCAP);
    unsigned short* WB = Tb + 512 * 128;
    unsigned* nfb32 = (unsigned*)(WB + 16384);

    hipMemsetAsync(cursor, 0, (size_t)NBK * sizeof(unsigned), stream);

    int nfb_blocks = (N * D / 4 + 255) / 256;   // 6250
    build_kernel<<<eb + 320 + nfb_blocks, 256, 0, stream>>>(
        src, dst, eidx, emb, Wm, nfeat, cursor, bucket, Tb, WB, nfb32, E, eb);
    fused_gp<<<NBK, 256, 0, stream>>>(
        nfeat, nfb32, (const unsigned*)Tb, bucket, cursor, WB, bias, out, N);
}